// Round 1
// baseline (1376.899 us; speedup 1.0000x reference)
//
#include <hip/hip_runtime.h>

#define NBINS 16

// acc layout in d_ws (49 floats):
//   acc[0]        : sum of (wq - w)^2
//   acc[1 .. 16]  : per-bin count
//   acc[17 .. 32] : per-bin sum of w
//   acc[33 .. 48] : per-bin sum of w*w

__global__ __launch_bounds__(256) void binreg_main(
    const float* __restrict__ w, const float* __restrict__ wq,
    const float* __restrict__ alpha_p, const int* __restrict__ nbit_p,
    float* __restrict__ acc, long long n)
{
    // one histogram replica per wave (4 waves / 256-thread block),
    // 48-float stride staggers replicas across the 32 LDS banks
    __shared__ float h[4][3][NBINS];
    __shared__ float sqpart[4];
    const int tid  = threadIdx.x;
    const int wave = tid >> 6;
    float* hflat = &h[0][0][0];

    for (int i = tid; i < 4 * 3 * NBINS; i += 256) hflat[i] = 0.0f;
    __syncthreads();

    const float inv_a = 1.0f / alpha_p[0];
    const int   qoff  = 1 << (nbit_p[0] - 1);   // -Qn = 8 for nbit=4

    const long long n4     = n >> 2;
    const long long stride = (long long)gridDim.x * 256;
    const float4* w4 = (const float4*)w;
    const float4* q4 = (const float4*)wq;

    float sq = 0.0f;

    for (long long i = (long long)blockIdx.x * 256 + tid; i < n4; i += stride) {
        float4 a = w4[i];
        float4 b = q4[i];

        float d0 = b.x - a.x, d1 = b.y - a.y, d2 = b.z - a.z, d3 = b.w - a.w;
        sq += d0 * d0 + d1 * d1 + d2 * d2 + d3 * d3;

        int b0 = min(max((int)rintf(b.x * inv_a) + qoff, 0), NBINS - 1);
        int b1 = min(max((int)rintf(b.y * inv_a) + qoff, 0), NBINS - 1);
        int b2 = min(max((int)rintf(b.z * inv_a) + qoff, 0), NBINS - 1);
        int b3 = min(max((int)rintf(b.w * inv_a) + qoff, 0), NBINS - 1);

        atomicAdd(&h[wave][0][b0], 1.0f);
        atomicAdd(&h[wave][1][b0], a.x);
        atomicAdd(&h[wave][2][b0], a.x * a.x);

        atomicAdd(&h[wave][0][b1], 1.0f);
        atomicAdd(&h[wave][1][b1], a.y);
        atomicAdd(&h[wave][2][b1], a.y * a.y);

        atomicAdd(&h[wave][0][b2], 1.0f);
        atomicAdd(&h[wave][1][b2], a.z);
        atomicAdd(&h[wave][2][b2], a.z * a.z);

        atomicAdd(&h[wave][0][b3], 1.0f);
        atomicAdd(&h[wave][1][b3], a.w);
        atomicAdd(&h[wave][2][b3], a.w * a.w);
    }

    // scalar tail (N is divisible by 4 in practice; this is just safety)
    for (long long i = (n4 << 2) + (long long)blockIdx.x * 256 + tid; i < n; i += stride) {
        float a = w[i], b = wq[i];
        float d = b - a;
        sq += d * d;
        int bb = min(max((int)rintf(b * inv_a) + qoff, 0), NBINS - 1);
        atomicAdd(&h[wave][0][bb], 1.0f);
        atomicAdd(&h[wave][1][bb], a);
        atomicAdd(&h[wave][2][bb], a * a);
    }

    // wave-reduce sq (64 lanes), then block-reduce via LDS
    for (int off = 32; off > 0; off >>= 1) sq += __shfl_down(sq, off, 64);
    if ((tid & 63) == 0) sqpart[wave] = sq;
    __syncthreads();

    if (tid == 0)
        atomicAdd(&acc[0], sqpart[0] + sqpart[1] + sqpart[2] + sqpart[3]);

    // threads 0..47 each fold the 4 wave replicas of one (stat,bin) cell
    if (tid < 3 * NBINS) {
        float v = hflat[tid] + hflat[48 + tid] + hflat[96 + tid] + hflat[144 + tid];
        atomicAdd(&acc[1 + tid], v);
    }
}

__global__ void binreg_final(const float* __restrict__ acc,
                             float* __restrict__ out, long long n)
{
    if (threadIdx.x == 0 && blockIdx.x == 0) {
        float loss = acc[0] / (float)n;   // mean squared diff
        #pragma unroll
        for (int b = 0; b < NBINS; ++b) {
            float cnt = acc[1 + b];
            float s   = acc[17 + b];
            float ss  = acc[33 + b];
            if (cnt > 1.0f) {
                float var = (ss - s * s / cnt) / (cnt - 1.0f);  // unbiased
                loss += var;
            }
        }
        out[0] = 0.1f * loss;   // LMBDA
    }
}

extern "C" void kernel_launch(void* const* d_in, const int* in_sizes, int n_in,
                              void* d_out, int out_size, void* d_ws, size_t ws_size,
                              hipStream_t stream)
{
    const float* w     = (const float*)d_in[0];
    const float* wq    = (const float*)d_in[1];
    const int*   nbit  = (const int*)d_in[2];
    const float* alpha = (const float*)d_in[3];
    float* out = (float*)d_out;
    float* acc = (float*)d_ws;
    long long n = (long long)in_sizes[0];

    // zero the 49-float accumulator block (d_ws is poisoned to 0xAA each call)
    hipMemsetAsync(acc, 0, 49 * sizeof(float), stream);

    // 4096 blocks x 256 threads: 16 blocks/CU queued, each thread ~16 float4 iters
    binreg_main<<<4096, 256, 0, stream>>>(w, wq, alpha, nbit, acc, n);
    binreg_final<<<1, 64, 0, stream>>>(acc, out, n);
}

// Round 2
// 556.375 us; speedup vs baseline: 2.4748x; 2.4748x over previous
//
#include <hip/hip_runtime.h>

#define NBINS  16
#define STRIDE 17          // per-thread LDS stride in words; odd -> 2-way bank aliasing (free)
#define BLOCKS 768         // exactly 3 blocks/CU co-resident (LDS-bound occupancy)
#define TPB    256

// d_ws layout: partial[cell * BLOCKS + blockIdx], cells: 0..15 cnt, 16..31 sum,
// 32..47 sumsq, 48 = sum of (wq-w)^2.  49*768 floats = 150 KB.

__global__ __launch_bounds__(TPB) void binreg_main(
    const float* __restrict__ w, const float* __restrict__ wq,
    const float* __restrict__ alpha_p, const int* __restrict__ nbit_p,
    float* __restrict__ partial, long long n)
{
    // one private histogram per THREAD -> zero atomics, zero contention
    __shared__ float s_pl [TPB * STRIDE];
    __shared__ float ss_pl[TPB * STRIDE];
    __shared__ float c_pl [TPB * STRIDE];
    __shared__ float sqpart[TPB / 64];

    const int tid = threadIdx.x;
    const int tb  = tid * STRIDE;

    #pragma unroll
    for (int k = 0; k < NBINS; ++k) {
        s_pl [tb + k] = 0.0f;
        ss_pl[tb + k] = 0.0f;
        c_pl [tb + k] = 0.0f;
    }
    // each thread touched only its own region; no sync needed until epilogue

    const float inv_a = 1.0f / alpha_p[0];
    const int   qoff  = 1 << (nbit_p[0] - 1);   // -Qn = 8 for nbit=4

    const long long n4     = n >> 2;
    const long long stride = (long long)BLOCKS * TPB;
    const float4* w4 = (const float4*)w;
    const float4* q4 = (const float4*)wq;

    float sq = 0.0f;

    for (long long i = (long long)blockIdx.x * TPB + tid; i < n4; i += stride) {
        float4 a = w4[i];
        float4 b = q4[i];

        float d0 = b.x - a.x, d1 = b.y - a.y, d2 = b.z - a.z, d3 = b.w - a.w;
        sq += d0 * d0 + d1 * d1 + d2 * d2 + d3 * d3;

        int i0 = tb + (((int)rintf(b.x * inv_a) + qoff) & (NBINS - 1));
        int i1 = tb + (((int)rintf(b.y * inv_a) + qoff) & (NBINS - 1));
        int i2 = tb + (((int)rintf(b.z * inv_a) + qoff) & (NBINS - 1));
        int i3 = tb + (((int)rintf(b.w * inv_a) + qoff) & (NBINS - 1));

        c_pl[i0] += 1.0f;  s_pl[i0] += a.x;  ss_pl[i0] += a.x * a.x;
        c_pl[i1] += 1.0f;  s_pl[i1] += a.y;  ss_pl[i1] += a.y * a.y;
        c_pl[i2] += 1.0f;  s_pl[i2] += a.z;  ss_pl[i2] += a.z * a.z;
        c_pl[i3] += 1.0f;  s_pl[i3] += a.w;  ss_pl[i3] += a.w * a.w;
    }

    // scalar tail (n divisible by 4 here; safety only)
    for (long long i = (n4 << 2) + (long long)blockIdx.x * TPB + tid; i < n; i += stride) {
        float a = w[i], b = wq[i];
        float d = b - a;
        sq += d * d;
        int ii = tb + (((int)rintf(b * inv_a) + qoff) & (NBINS - 1));
        c_pl[ii] += 1.0f;  s_pl[ii] += a;  ss_pl[ii] += a * a;
    }

    // wave-reduce sq
    for (int off = 32; off; off >>= 1) sq += __shfl_down(sq, off, 64);
    const int wave = tid >> 6, lane = tid & 63;
    if (lane == 0) sqpart[wave] = sq;
    __syncthreads();

    // fold 256 private histograms -> 48 block partials; wave w handles cells w, w+4, ...
    for (int c = wave; c < 48; c += 4) {
        const float* pl = (c < 16) ? c_pl : (c < 32) ? s_pl : ss_pl;
        const int bin = c & 15;
        float v = 0.0f;
        #pragma unroll
        for (int r = 0; r < TPB / 64; ++r)
            v += pl[(r * 64 + lane) * STRIDE + bin];
        for (int off = 32; off; off >>= 1) v += __shfl_down(v, off, 64);
        if (lane == 0) partial[c * BLOCKS + blockIdx.x] = v;
    }
    if (tid == 0)
        partial[48 * BLOCKS + blockIdx.x] =
            sqpart[0] + sqpart[1] + sqpart[2] + sqpart[3];
}

__global__ __launch_bounds__(TPB) void binreg_final(
    const float* __restrict__ partial, float* __restrict__ out, long long n)
{
    __shared__ float cell[49];
    const int tid = threadIdx.x, wave = tid >> 6, lane = tid & 63;

    for (int c = wave; c < 49; c += 4) {
        float v = 0.0f;
        for (int r = lane; r < BLOCKS; r += 64) v += partial[c * BLOCKS + r];
        for (int off = 32; off; off >>= 1) v += __shfl_down(v, off, 64);
        if (lane == 0) cell[c] = v;
    }
    __syncthreads();

    if (tid == 0) {
        float loss = cell[48] / (float)n;   // mean squared diff
        #pragma unroll
        for (int b = 0; b < NBINS; ++b) {
            float cnt = cell[b];
            float s   = cell[16 + b];
            float ss  = cell[32 + b];
            if (cnt > 1.0f)
                loss += (ss - s * s / cnt) / (cnt - 1.0f);  // unbiased var
        }
        out[0] = 0.1f * loss;   // LMBDA
    }
}

extern "C" void kernel_launch(void* const* d_in, const int* in_sizes, int n_in,
                              void* d_out, int out_size, void* d_ws, size_t ws_size,
                              hipStream_t stream)
{
    const float* w     = (const float*)d_in[0];
    const float* wq    = (const float*)d_in[1];
    const int*   nbit  = (const int*)d_in[2];
    const float* alpha = (const float*)d_in[3];
    float* out     = (float*)d_out;
    float* partial = (float*)d_ws;   // fully overwritten each call; no memset needed
    long long n = (long long)in_sizes[0];

    binreg_main<<<BLOCKS, TPB, 0, stream>>>(w, wq, alpha, nbit, partial, n);
    binreg_final<<<1, TPB, 0, stream>>>(partial, out, n);
}